// Round 2
// baseline (64.132 us; speedup 1.0000x reference)
//
#include <hip/hip_runtime.h>

// QuantizedLinear: out[8,8192] = x[8,8192] @ W^T, W = dequant4(qweight, scale, zero)
// qweight packed 2 nibbles/byte (low first), delivered as int32 (one 0..255 per int).
// GROUP=128 -> 64 packed ints per group.
//
// Layout: each wave owns RPW=4 output rows and one K-half (K-split=2, atomicAdd).
// Per iteration a lane loads int4 (4 packed ints = 8 k-values); 64 lanes cover
// 256 packed = 512 k = 4 groups. Lane's group = g4*4 + (lane>>4).

constexpr int M      = 8;
constexpr int OUTF   = 8192;
constexpr int INF    = 8192;
constexpr int NGROUP = 64;            // IN / GROUP
constexpr int PK4ROW = INF / 8;       // 1024 int4 per output row
constexpr int RPW    = 4;             // rows per wave
constexpr int WPB    = 4;             // waves per block (256 threads)
constexpr int KS     = 2;             // K splits
constexpr int NITER  = 16 / KS;       // dwordx4-iterations per K-half (16 total)

__global__ __launch_bounds__(256, 4) void qlin4_kernel(
    const float* __restrict__ x,      // [8, 8192]
    const int*   __restrict__ qw,     // [8192, 4096] values 0..255
    const float* __restrict__ scale,  // [8192, 64]
    const float* __restrict__ zero,   // [8192, 64]
    float*       __restrict__ out)    // [8, 8192] (pre-zeroed; atomicAdd)
{
    const int lane = threadIdx.x & 63;
    const int wave = threadIdx.x >> 6;
    const int bid  = blockIdx.x;
    const int ks   = bid >> 9;                       // 0 or 1 (grid = 1024)
    const int n0   = (bid & 511) * (WPB * RPW) + wave * RPW;

    float acc[M][RPW];
    #pragma unroll
    for (int m = 0; m < M; ++m)
        #pragma unroll
        for (int r = 0; r < RPW; ++r) acc[m][r] = 0.0f;

    const int4*   __restrict__ qw4 = reinterpret_cast<const int4*>(qw);
    const float4* __restrict__ x4  = reinterpret_cast<const float4*>(x);  // [8][2048]

    for (int t = 0; t < NITER; ++t) {
        const int g4 = ks * NITER + t;               // which 512-k chunk

        // Weights: lane covers packed ints [g4*256 + 4*lane .. +3] of each row.
        int4 q[RPW];
        #pragma unroll
        for (int r = 0; r < RPW; ++r)
            q[r] = qw4[(size_t)(n0 + r) * PK4ROW + (g4 * 64 + lane)];

        // This lane's quant group within the 4-group chunk.
        const int gidx = g4 * 4 + (lane >> 4);
        float s[RPW], zs[RPW];
        #pragma unroll
        for (int r = 0; r < RPW; ++r) {
            const float sc = scale[(n0 + r) * NGROUP + gidx];
            s[r]  = sc;
            zs[r] = zero[(n0 + r) * NGROUP + gidx] * sc;
        }

        // Dequant 8 k-values per row: w[2i] = low nibble of int i, w[2i+1] = high.
        float w[RPW][8];
        #pragma unroll
        for (int r = 0; r < RPW; ++r) {
            const int* qi = reinterpret_cast<const int*>(&q[r]);
            #pragma unroll
            for (int i = 0; i < 4; ++i) {
                w[r][2 * i]     = fmaf((float)(qi[i] & 15),        s[r], -zs[r]);
                w[r][2 * i + 1] = fmaf((float)((qi[i] >> 4) & 15), s[r], -zs[r]);
            }
        }

        // x: lane covers k = g4*512 + 8*lane .. +7  -> two float4 per m.
        #pragma unroll
        for (int m = 0; m < M; ++m) {
            const float4 xa = x4[m * (INF / 4) + g4 * 128 + 2 * lane];
            const float4 xb = x4[m * (INF / 4) + g4 * 128 + 2 * lane + 1];
            #pragma unroll
            for (int r = 0; r < RPW; ++r) {
                float a = acc[m][r];
                a = fmaf(w[r][0], xa.x, a);
                a = fmaf(w[r][1], xa.y, a);
                a = fmaf(w[r][2], xa.z, a);
                a = fmaf(w[r][3], xa.w, a);
                a = fmaf(w[r][4], xb.x, a);
                a = fmaf(w[r][5], xb.y, a);
                a = fmaf(w[r][6], xb.z, a);
                a = fmaf(w[r][7], xb.w, a);
                acc[m][r] = a;
            }
        }
    }

    // Wave-wide butterfly reduction; one atomicAdd per (m, r).
    #pragma unroll
    for (int m = 0; m < M; ++m) {
        #pragma unroll
        for (int r = 0; r < RPW; ++r) {
            float v = acc[m][r];
            #pragma unroll
            for (int off = 32; off > 0; off >>= 1)
                v += __shfl_xor(v, off, 64);
            if (lane == 0)
                atomicAdd(&out[m * OUTF + (n0 + r)], v);
        }
    }
}

extern "C" void kernel_launch(void* const* d_in, const int* in_sizes, int n_in,
                              void* d_out, int out_size, void* d_ws, size_t ws_size,
                              hipStream_t stream) {
    const float* x     = (const float*)d_in[0];
    const int*   qw    = (const int*)d_in[1];
    const float* scale = (const float*)d_in[2];
    const float* zero  = (const float*)d_in[3];
    float*       out   = (float*)d_out;

    hipMemsetAsync(out, 0, (size_t)M * OUTF * sizeof(float), stream);

    const int blocks = (OUTF / (WPB * RPW)) * KS;  // 512 * 2 = 1024
    qlin4_kernel<<<blocks, 256, 0, stream>>>(x, qw, scale, zero, out);
}